// Round 6
// baseline (531.290 us; speedup 1.0000x reference)
//
#include <hip/hip_runtime.h>

// Fastformer additive attention, MI355X (round 12):
//   - conv / gemm_k (QK, VU, OUT) reverted VERBATIM to round 9 (183.1us).
//   - stage_soft (measured 48.2us each, 96us total, all pipes idle: per-mi
//     serial global-load chain at 2-3 waves/SIMD) REPLACED by stage_gemm:
//     block = 128 n-rows x 1 head (512 blocks); A-tile staged once via
//     gload16+XOR-swizzle, A-frags in regs; wq/wk streamed in 8x128-row
//     LDS chunks with the r9-proven dbuf schedule; exp + z/w accumulate
//     fully in-register; m entirely in-wave -> 16-lane shfl reduce, no
//     cross-wave LDS reduce, no atomics; qg=W/Z written directly.
// Pipeline: conv -> QK(+qsks) -> stage1 -> stage2 -> VU -> OUT  (6 launches)

#define SCL2 0.1803368801f   /* 0.125 * log2(e) */
typedef unsigned short u16;
typedef __attribute__((ext_vector_type(8))) short short8;   // 8 bf16 = 4 VGPR
typedef __attribute__((ext_vector_type(4))) float f32x4;

#define MFMA16(a, b, c) __builtin_amdgcn_mfma_f32_16x16x32_bf16((a), (b), (c), 0, 0, 0)

__device__ __forceinline__ float bf2f(u16 u) {
    union { unsigned int i; float f; } v; v.i = ((unsigned int)u) << 16; return v.f;
}
__device__ __forceinline__ u16 f2bf(float f) {
    union { float f; unsigned int i; } v; v.f = f;
    unsigned int x = v.i;
    return (u16)((x + 0x7FFFu + ((x >> 16) & 1u)) >> 16);
}

// async global->LDS, 16B per lane; LDS dest = wave-uniform base + lane*16
__device__ __forceinline__ void gload16(const u16* g, u16* l) {
    __builtin_amdgcn_global_load_lds(
        (__attribute__((address_space(1))) void*)(void*)g,
        (__attribute__((address_space(3))) void*)l, 16, 0, 0);
}

// ---------------------------------------------------------------------------
// f32 -> bf16: w_qkv | w_out | wq | wk | x   (contiguous ws block)
// ---------------------------------------------------------------------------
__global__ __launch_bounds__(256) void conv_kernel(
    const float* __restrict__ w_qkv, const float* __restrict__ w_out,
    const float* __restrict__ wq, const float* __restrict__ wk,
    const float* __restrict__ x, u16* __restrict__ wsb)
{
    const int idx = (blockIdx.x * 256 + threadIdx.x) * 4;
    const float* src; int off;
    if      (idx < 786432)  { src = w_qkv; off = idx; }
    else if (idx < 1048576) { src = w_out; off = idx - 786432; }
    else if (idx < 1114112) { src = wq;    off = idx - 1048576; }
    else if (idx < 1179648) { src = wk;    off = idx - 1114112; }
    else                    { src = x;     off = idx - 1179648; }
    float4 v = *(const float4*)(src + off);
    ushort4 o; o.x = f2bf(v.x); o.y = f2bf(v.y); o.z = f2bf(v.z); o.w = f2bf(v.w);
    *(ushort4*)(wsb + idx) = o;
}

// ---------------------------------------------------------------------------
// MFMA GEMM (round-9 verbatim): tile 128M x (NCT*16)N, BK=64, K=512, 4 waves.
// Double-buffered gload_lds staging (linear LDS dest, source chunk swizzled
// with (lane&7)^(lane>>3)); fragment reads XOR chunk idx with (row&7).
// K-loop: stage(next buf) -> sched_barrier -> compute(cur) -> syncthreads.
// Final compute reads buf0; C bounce (padded stride) overlays buf1.
// ---------------------------------------------------------------------------
#define MQK 0
#define MVU 1
#define MOUT 2

template <int MODE, int NCT>
__global__ __launch_bounds__(256) void gemm_k(
    const u16* __restrict__ Ab, int lda, int acol,
    const u16* __restrict__ Wb, const float* __restrict__ bias,
    const float* __restrict__ kg, const u16* __restrict__ qkws_ro,
    u16* __restrict__ qkws, float* __restrict__ outp,
    float* __restrict__ qsout, float* __restrict__ ksout)
{
    constexpr int BN = NCT * 16;            // tile N
    constexpr int CST = BN + 8;             // padded bounce stride (u16)
    constexpr int ASZ = 128 * 64;           // A elems per buffer
    constexpr int BSZ = BN * 64;            // B elems per buffer
    constexpr int HALF = ASZ + BSZ;         // one double-buffer half
    constexpr int CELEM = 128 * CST;
    constexpr int SMSZ = (2 * HALF > HALF + CELEM) ? 2 * HALF : HALF + CELEM;
    __shared__ u16 sm[SMSZ];
    u16* const Cb = sm + HALF;              // C bounce overlays buf1 only

    const int t = threadIdx.x;
    const int w = t >> 6, lane = t & 63, s = lane & 15, quad = lane >> 4;
    const int sx = lane & 7;                // row&7 of every fragment row read

    // T1: bijective XCD swizzle (nwg % 8 == 0)
    const int nwgy = gridDim.y;
    const int nwg = gridDim.x * nwgy;
    const int flat = blockIdx.y * gridDim.x + blockIdx.x;
    const int swz = (flat & 7) * (nwg >> 3) + (flat >> 3);
    const int by = swz % nwgy, bx = swz / nwgy;
    const int bm = bx * 128, jn0 = by * BN;

    const int r8 = lane >> 3;                       // staged row within 8-row group
    const int c8x = ((lane & 7) ^ r8) << 3;         // swizzled source chunk (u16)

    f32x4 acc[2][NCT];
#pragma unroll
    for (int i = 0; i < 2; ++i)
#pragma unroll
        for (int j = 0; j < NCT; ++j) acc[i][j] = (f32x4){0.f, 0.f, 0.f, 0.f};

    // per-wave staging bases: A rows [w*32, w*32+32), B rows [w*NCT*4, ...)
    const u16* ga = Ab + (size_t)(bm + w * 32 + r8) * lda + acol + c8x;
    const u16* gb = Wb + (size_t)(jn0 + w * (NCT * 4) + r8) * 512 + c8x;

    auto stage = [&](int buf, int kt) {
        u16* la = sm + buf * HALF + (w * 32) * 64;
        u16* lb = sm + buf * HALF + ASZ + (w * (NCT * 4)) * 64;
#pragma unroll
        for (int j = 0; j < 4; ++j)
            gload16(ga + (size_t)j * 8 * lda + kt, la + j * 8 * 64);
#pragma unroll
        for (int j = 0; j < NCT / 2; ++j)
            gload16(gb + (size_t)j * 8 * 512 + kt, lb + j * 8 * 64);
    };
    auto compute = [&](int buf) {
        const u16* Ab_ = sm + buf * HALF;
        const u16* Bb_ = Ab_ + ASZ;
#pragma unroll
        for (int kk = 0; kk < 2; ++kk) {
            const int ca = ((kk * 4 + quad) ^ sx) << 3;   // swizzled read chunk
            short8 a0 = *(const short8*)&Ab_[(w * 32 + s) * 64 + ca];
            short8 a1 = *(const short8*)&Ab_[(w * 32 + 16 + s) * 64 + ca];
#pragma unroll
            for (int ct = 0; ct < NCT; ++ct) {
                short8 bf = *(const short8*)&Bb_[(ct * 16 + s) * 64 + ca];
                acc[0][ct] = MFMA16(a0, bf, acc[0][ct]);
                acc[1][ct] = MFMA16(a1, bf, acc[1][ct]);
            }
        }
    };

    // Pipeline: prologue stages tile0 into buf1; computes alternate 1,0,1,...
    stage(1, 0);
    __syncthreads();
#pragma unroll
    for (int it = 0; it < 7; ++it) {
        const int cur = 1 - (it & 1);
        stage(1 - cur, 64 * (it + 1));            // issue next-tile loads
        __builtin_amdgcn_sched_barrier(0);        // pin issue-before-compute
        compute(cur);
        __syncthreads();                          // drains prefetch; guards WAR
    }
    compute(0);

    if constexpr (MODE == MOUT) {
#pragma unroll
        for (int mt = 0; mt < 2; ++mt)
#pragma unroll
            for (int ct = 0; ct < NCT; ++ct) {
                const int jn = jn0 + ct * 16 + s;
#pragma unroll
                for (int r = 0; r < 4; ++r) {
                    const int row = bm + w * 32 + mt * 16 + quad * 4 + r;
                    outp[(size_t)row * 512 + jn] =
                        acc[mt][ct][r] + bias[jn] + bf2f(qkws_ro[(size_t)row * 1024 + jn]);
                }
            }
    } else {
        float rsum[2][NCT / 4][4];
        if constexpr (MODE == MQK) {
#pragma unroll
            for (int mt = 0; mt < 2; ++mt)
#pragma unroll
                for (int hg = 0; hg < NCT / 4; ++hg)
#pragma unroll
                    for (int r = 0; r < 4; ++r) rsum[mt][hg][r] = 0.f;
        }
        __syncthreads();   // final-buf reads (buf0) done; C overlays buf1
#pragma unroll
        for (int mt = 0; mt < 2; ++mt)
#pragma unroll
            for (int ct = 0; ct < NCT; ++ct) {
                const int jn = jn0 + ct * 16 + s;
                const float bj = bias[jn];
#pragma unroll
                for (int r = 0; r < 4; ++r) {
                    const int rowl = w * 32 + mt * 16 + quad * 4 + r;
                    float v = acc[mt][ct][r] + bj;
                    if constexpr (MODE == MVU) {
                        const int row = bm + rowl;
                        v *= kg[(((row >> 10) * 8 + (jn >> 6)) << 10) | (row & 1023)];
                    }
                    if constexpr (MODE == MQK) rsum[mt][ct >> 2][r] += v;
                    Cb[rowl * CST + ct * 16 + s] = f2bf(v);
                }
            }
        if constexpr (MODE == MQK) {
            // fused qs/ks: per-row sum over each 64-col head group
#pragma unroll
            for (int mt = 0; mt < 2; ++mt)
#pragma unroll
                for (int hg = 0; hg < NCT / 4; ++hg)
#pragma unroll
                    for (int r = 0; r < 4; ++r) {
                        float S = rsum[mt][hg][r];
                        S += __shfl_xor(S, 1);
                        S += __shfl_xor(S, 2);
                        S += __shfl_xor(S, 4);
                        S += __shfl_xor(S, 8);
                        if (s == 0) {
                            const int row = bm + w * 32 + mt * 16 + quad * 4 + r;
                            const int jj = jn0 + hg * 64;
                            float* dst = (jj < 512) ? qsout : ksout;
                            dst[((((row >> 10) << 3) | ((jj >> 6) & 7)) << 10) | (row & 1023)] = S;
                        }
                    }
        }
        __syncthreads();
        const int row = t >> 1, ch = (t & 1) * (NCT * 8);
        u16* dp = qkws + (size_t)(bm + row) * 1024 + (MODE == MVU ? 512 : 0) + jn0 + ch;
#pragma unroll
        for (int i = 0; i < NCT; ++i)
            *(uint4*)(dp + i * 8) = *(const uint4*)&Cb[row * CST + ch + i * 8];
    }
}

// ---------------------------------------------------------------------------
// stage_gemm: softmax-stage as a chunked GEMM. Block = (128 n-rows, head h);
// grid 512 = 64 n-tiles x 8 heads. Wave owns 32 n-rows x ALL 1024 m.
//   A-tile (q or k slice, 128x64) staged once via gload16+swizzle; A-frags
//   held in registers. B (wq/wk) streamed in 8 chunks of 128 rows through a
//   double-buffered LDS pipeline (r9 schedule). Per chunk: 32 MFMA + 64 exp
//   + z/w fma per wave, bias/wv loaded up-front. m fully in-wave -> 16-lane
//   shfl reduce; out = W/Z written directly.
//   STG=1: l=(q.wq+bq)*S,            wv=qs      -> qg
//   STG=2: l=(rs*(k.wk)+bk)*S, rs=qg, wv=qg*ks  -> kg
// ---------------------------------------------------------------------------
template <int STG>
__global__ __launch_bounds__(256) void stage_gemm(
    const u16* __restrict__ qkws, int qcol0,
    const u16* __restrict__ wmb, const float* __restrict__ biasv,
    const float* __restrict__ rowscale,
    const float* __restrict__ wv1, const float* __restrict__ wv2,
    float* __restrict__ outg)
{
    __shared__ u16 sm[24576];               // A 8192 | Bbuf0 8192 | Bbuf1 8192
    u16* const As = sm;

    const int t = threadIdx.x;
    const int w = t >> 6, lane = t & 63, s = lane & 15, quad = lane >> 4;
    const int sx = lane & 7;
    const int r8 = lane >> 3;
    const int c8x = ((lane & 7) ^ r8) << 3;         // swizzled source chunk (u16)

    // XCD swizzle over 512 blocks
    const int flat = blockIdx.y * gridDim.x + blockIdx.x;
    const int swz = (flat & 7) * 64 + (flat >> 3);
    const int h = swz & 7, bx = swz >> 3;
    const int bm = bx * 128;                        // row in 8192-space
    const int bh = ((bm >> 10) << 3) + h;
    const int n0 = bm & 1023;

    // staging bases: A rows bm+w*32+r8(+8j), 64 cols at qcol0+h*64
    const u16* gA = qkws + (size_t)(bm + w * 32 + r8) * 1024 + qcol0 + (h << 6) + c8x;
    const u16* gB = wmb + (size_t)(w * 32 + r8) * 64 + c8x;

    auto stageB = [&](int buf, int c) {
        u16* lb = sm + 8192 + buf * 8192 + (w * 32) * 64;
        const u16* g = gB + (size_t)c * 128 * 64;
#pragma unroll
        for (int j = 0; j < 4; ++j)
            gload16(g + (size_t)j * 8 * 64, lb + j * 8 * 64);
    };

    // prologue: A once + B chunk0 into buf1
#pragma unroll
    for (int j = 0; j < 4; ++j)
        gload16(gA + (size_t)j * 8 * 1024, As + (w * 32 + j * 8) * 64);
    stageB(1, 0);
    __syncthreads();

    // A fragments in registers for the whole kernel
    short8 a[2][2];
#pragma unroll
    for (int nt = 0; nt < 2; ++nt)
#pragma unroll
        for (int kk = 0; kk < 2; ++kk)
            a[nt][kk] = *(const short8*)&As[(w * 32 + nt * 16 + s) * 64 + (((kk * 4 + quad) ^ sx) << 3)];

    float rsf[2][4];
#pragma unroll
    for (int nt = 0; nt < 2; ++nt)
#pragma unroll
        for (int r = 0; r < 4; ++r) {
            if constexpr (STG == 2)
                rsf[nt][r] = rowscale[(bh << 10) + n0 + w * 32 + nt * 16 + quad * 4 + r] * SCL2;
            else
                rsf[nt][r] = SCL2;
        }

    float z[2][4] = {}, wacc[2][4] = {};

#pragma unroll
    for (int c = 0; c < 8; ++c) {
        const int cur = 1 - (c & 1);
        if (c < 7) stageB(1 - cur, c + 1);          // issue next-chunk loads
        __builtin_amdgcn_sched_barrier(0);

        // bias / wv for this chunk (L2-hot, independent loads)
        const int mb = c * 128;
        float bmv[8], wvv[8];
#pragma unroll
        for (int ct = 0; ct < 8; ++ct) {
            const int m = mb + ct * 16 + s;
            bmv[ct] = biasv[m] * SCL2;
            float wv = wv1[(bh << 10) + m];
            if constexpr (STG == 2) wv *= wv2[(bh << 10) + m];
            wvv[ct] = wv;
        }

        const u16* Bb = sm + 8192 + cur * 8192;
#pragma unroll
        for (int ct = 0; ct < 8; ++ct) {
            const short8 b0 = *(const short8*)&Bb[(ct * 16 + s) * 64 + ((quad ^ sx) << 3)];
            const short8 b1 = *(const short8*)&Bb[(ct * 16 + s) * 64 + (((4 + quad) ^ sx) << 3)];
#pragma unroll
            for (int nt = 0; nt < 2; ++nt) {
                f32x4 acc = (f32x4){0.f, 0.f, 0.f, 0.f};
                acc = MFMA16(a[nt][0], b0, acc);
                acc = MFMA16(a[nt][1], b1, acc);
#pragma unroll
                for (int r = 0; r < 4; ++r) {
                    const float e = __builtin_amdgcn_exp2f(rsf[nt][r] * acc[r] + bmv[ct]);
                    z[nt][r] += e;
                    wacc[nt][r] += e * wvv[ct];
                }
            }
        }
        __syncthreads();                            // chunk consumed; WAR-safe
    }

    // reduce over the 16 m-lanes; s==0 writes out = W/Z
#pragma unroll
    for (int nt = 0; nt < 2; ++nt)
#pragma unroll
        for (int r = 0; r < 4; ++r) {
            float Z = z[nt][r], W = wacc[nt][r];
            for (int off = 1; off < 16; off <<= 1) {
                Z += __shfl_xor(Z, off);
                W += __shfl_xor(W, off);
            }
            if (s == 0)
                outg[(bh << 10) + n0 + w * 32 + nt * 16 + quad * 4 + r] = W / Z;
        }
}

// ---------------------------------------------------------------------------
extern "C" void kernel_launch(void* const* d_in, const int* in_sizes, int n_in,
                              void* d_out, int out_size, void* d_ws, size_t ws_size,
                              hipStream_t stream)
{
    const float* x     = (const float*)d_in[0];
    const float* w_qkv = (const float*)d_in[1];
    const float* b_qkv = (const float*)d_in[2];
    const float* wq    = (const float*)d_in[3];
    const float* bq    = (const float*)d_in[4];
    const float* wk    = (const float*)d_in[5];
    const float* bk    = (const float*)d_in[6];
    const float* w_out = (const float*)d_in[7];
    const float* b_out = (const float*)d_in[8];
    float* out = (float*)d_out;

    // ws: qs|ks|qg|kg (65536 f32) | bf16: wqkv|wout|wq|wk|x | qk ws bf16
    float* qs = (float*)d_ws;
    float* ks = qs + 65536;
    float* qg = ks + 65536;
    float* kg = qg + 65536;
    u16* wsb   = (u16*)(kg + 65536);
    u16* wqkvb = wsb;
    u16* woutb = wqkvb + 786432;
    u16* wqb   = woutb + 262144;
    u16* wkb   = wqb + 65536;
    u16* xb    = wkb + 65536;
    u16* qkws  = xb + 4194304;

    // 5,373,952 f32 -> bf16 (weights + x), 4 elems/thread
    conv_kernel<<<5248, 256, 0, stream>>>(w_qkv, w_out, wq, wk, x, wsb);
    // QK: qk = x @ w_qkv[0:1024]^T + b_qkv  (128x128 tile) + fused qs/ks
    gemm_k<MQK, 8><<<dim3(64, 8), 256, 0, stream>>>(
        xb, 512, 0, wqkvb, b_qkv, nullptr, nullptr, qkws, nullptr, qs, ks);
    // stage 1 -> qg
    stage_gemm<1><<<dim3(64, 8), 256, 0, stream>>>(
        qkws, 0, wqb, bq, nullptr, qs, nullptr, qg);
    // stage 2 -> kg
    stage_gemm<2><<<dim3(64, 8), 256, 0, stream>>>(
        qkws, 512, wkb, bk, qg, qg, ks, kg);
    // VU: U = (x @ w_qkv[1024:]^T + bv) * kg  (into k-half of qk ws)
    gemm_k<MVU, 4><<<dim3(64, 8), 256, 0, stream>>>(
        xb, 512, 0, wqkvb + (size_t)1024 * 512, b_qkv + 1024, kg, nullptr, qkws,
        nullptr, nullptr, nullptr);
    // OUT: out = U @ w_out^T + b_out + qo
    gemm_k<MOUT, 4><<<dim3(64, 8), 256, 0, stream>>>(
        qkws, 1024, 512, woutb, b_out, nullptr, qkws, nullptr, out, nullptr, nullptr);
}

// Round 7
// 173.580 us; speedup vs baseline: 3.0608x; 3.0608x over previous
//
#include <hip/hip_runtime.h>

// Fastformer additive attention, MI355X (round 13):
//   - r12 structure, ONE change: stage_gemm's chunk loop is `#pragma unroll 1`.
//     r12's full unroll let the compiler hoist all 8 chunks' bias/wv global
//     loads (128 VGPR) -> 256 VGPR + ~1KB/thread scratch spill: measured
//     FETCH 210MB / WRITE 132MB / 219us per stage dispatch. unroll 1 bounds
//     the live set (~80 VGPR), killing the spill.
//   - conv / gemm_k (QK, VU, OUT) remain round-9 verbatim.
// Pipeline: conv -> QK(+qsks) -> stage1 -> stage2 -> VU -> OUT  (6 launches)

#define SCL2 0.1803368801f   /* 0.125 * log2(e) */
typedef unsigned short u16;
typedef __attribute__((ext_vector_type(8))) short short8;   // 8 bf16 = 4 VGPR
typedef __attribute__((ext_vector_type(4))) float f32x4;

#define MFMA16(a, b, c) __builtin_amdgcn_mfma_f32_16x16x32_bf16((a), (b), (c), 0, 0, 0)

__device__ __forceinline__ float bf2f(u16 u) {
    union { unsigned int i; float f; } v; v.i = ((unsigned int)u) << 16; return v.f;
}
__device__ __forceinline__ u16 f2bf(float f) {
    union { float f; unsigned int i; } v; v.f = f;
    unsigned int x = v.i;
    return (u16)((x + 0x7FFFu + ((x >> 16) & 1u)) >> 16);
}

// async global->LDS, 16B per lane; LDS dest = wave-uniform base + lane*16
__device__ __forceinline__ void gload16(const u16* g, u16* l) {
    __builtin_amdgcn_global_load_lds(
        (__attribute__((address_space(1))) void*)(void*)g,
        (__attribute__((address_space(3))) void*)l, 16, 0, 0);
}

// ---------------------------------------------------------------------------
// f32 -> bf16: w_qkv | w_out | wq | wk | x   (contiguous ws block)
// ---------------------------------------------------------------------------
__global__ __launch_bounds__(256) void conv_kernel(
    const float* __restrict__ w_qkv, const float* __restrict__ w_out,
    const float* __restrict__ wq, const float* __restrict__ wk,
    const float* __restrict__ x, u16* __restrict__ wsb)
{
    const int idx = (blockIdx.x * 256 + threadIdx.x) * 4;
    const float* src; int off;
    if      (idx < 786432)  { src = w_qkv; off = idx; }
    else if (idx < 1048576) { src = w_out; off = idx - 786432; }
    else if (idx < 1114112) { src = wq;    off = idx - 1048576; }
    else if (idx < 1179648) { src = wk;    off = idx - 1114112; }
    else                    { src = x;     off = idx - 1179648; }
    float4 v = *(const float4*)(src + off);
    ushort4 o; o.x = f2bf(v.x); o.y = f2bf(v.y); o.z = f2bf(v.z); o.w = f2bf(v.w);
    *(ushort4*)(wsb + idx) = o;
}

// ---------------------------------------------------------------------------
// MFMA GEMM (round-9 verbatim): tile 128M x (NCT*16)N, BK=64, K=512, 4 waves.
// Double-buffered gload_lds staging (linear LDS dest, source chunk swizzled
// with (lane&7)^(lane>>3)); fragment reads XOR chunk idx with (row&7).
// K-loop: stage(next buf) -> sched_barrier -> compute(cur) -> syncthreads.
// Final compute reads buf0; C bounce (padded stride) overlays buf1.
// ---------------------------------------------------------------------------
#define MQK 0
#define MVU 1
#define MOUT 2

template <int MODE, int NCT>
__global__ __launch_bounds__(256) void gemm_k(
    const u16* __restrict__ Ab, int lda, int acol,
    const u16* __restrict__ Wb, const float* __restrict__ bias,
    const float* __restrict__ kg, const u16* __restrict__ qkws_ro,
    u16* __restrict__ qkws, float* __restrict__ outp,
    float* __restrict__ qsout, float* __restrict__ ksout)
{
    constexpr int BN = NCT * 16;            // tile N
    constexpr int CST = BN + 8;             // padded bounce stride (u16)
    constexpr int ASZ = 128 * 64;           // A elems per buffer
    constexpr int BSZ = BN * 64;            // B elems per buffer
    constexpr int HALF = ASZ + BSZ;         // one double-buffer half
    constexpr int CELEM = 128 * CST;
    constexpr int SMSZ = (2 * HALF > HALF + CELEM) ? 2 * HALF : HALF + CELEM;
    __shared__ u16 sm[SMSZ];
    u16* const Cb = sm + HALF;              // C bounce overlays buf1 only

    const int t = threadIdx.x;
    const int w = t >> 6, lane = t & 63, s = lane & 15, quad = lane >> 4;
    const int sx = lane & 7;                // row&7 of every fragment row read

    // T1: bijective XCD swizzle (nwg % 8 == 0)
    const int nwgy = gridDim.y;
    const int nwg = gridDim.x * nwgy;
    const int flat = blockIdx.y * gridDim.x + blockIdx.x;
    const int swz = (flat & 7) * (nwg >> 3) + (flat >> 3);
    const int by = swz % nwgy, bx = swz / nwgy;
    const int bm = bx * 128, jn0 = by * BN;

    const int r8 = lane >> 3;                       // staged row within 8-row group
    const int c8x = ((lane & 7) ^ r8) << 3;         // swizzled source chunk (u16)

    f32x4 acc[2][NCT];
#pragma unroll
    for (int i = 0; i < 2; ++i)
#pragma unroll
        for (int j = 0; j < NCT; ++j) acc[i][j] = (f32x4){0.f, 0.f, 0.f, 0.f};

    // per-wave staging bases: A rows [w*32, w*32+32), B rows [w*NCT*4, ...)
    const u16* ga = Ab + (size_t)(bm + w * 32 + r8) * lda + acol + c8x;
    const u16* gb = Wb + (size_t)(jn0 + w * (NCT * 4) + r8) * 512 + c8x;

    auto stage = [&](int buf, int kt) {
        u16* la = sm + buf * HALF + (w * 32) * 64;
        u16* lb = sm + buf * HALF + ASZ + (w * (NCT * 4)) * 64;
#pragma unroll
        for (int j = 0; j < 4; ++j)
            gload16(ga + (size_t)j * 8 * lda + kt, la + j * 8 * 64);
#pragma unroll
        for (int j = 0; j < NCT / 2; ++j)
            gload16(gb + (size_t)j * 8 * 512 + kt, lb + j * 8 * 64);
    };
    auto compute = [&](int buf) {
        const u16* Ab_ = sm + buf * HALF;
        const u16* Bb_ = Ab_ + ASZ;
#pragma unroll
        for (int kk = 0; kk < 2; ++kk) {
            const int ca = ((kk * 4 + quad) ^ sx) << 3;   // swizzled read chunk
            short8 a0 = *(const short8*)&Ab_[(w * 32 + s) * 64 + ca];
            short8 a1 = *(const short8*)&Ab_[(w * 32 + 16 + s) * 64 + ca];
#pragma unroll
            for (int ct = 0; ct < NCT; ++ct) {
                short8 bf = *(const short8*)&Bb_[(ct * 16 + s) * 64 + ca];
                acc[0][ct] = MFMA16(a0, bf, acc[0][ct]);
                acc[1][ct] = MFMA16(a1, bf, acc[1][ct]);
            }
        }
    };

    // Pipeline: prologue stages tile0 into buf1; computes alternate 1,0,1,...
    stage(1, 0);
    __syncthreads();
#pragma unroll
    for (int it = 0; it < 7; ++it) {
        const int cur = 1 - (it & 1);
        stage(1 - cur, 64 * (it + 1));            // issue next-tile loads
        __builtin_amdgcn_sched_barrier(0);        // pin issue-before-compute
        compute(cur);
        __syncthreads();                          // drains prefetch; guards WAR
    }
    compute(0);

    if constexpr (MODE == MOUT) {
#pragma unroll
        for (int mt = 0; mt < 2; ++mt)
#pragma unroll
            for (int ct = 0; ct < NCT; ++ct) {
                const int jn = jn0 + ct * 16 + s;
#pragma unroll
                for (int r = 0; r < 4; ++r) {
                    const int row = bm + w * 32 + mt * 16 + quad * 4 + r;
                    outp[(size_t)row * 512 + jn] =
                        acc[mt][ct][r] + bias[jn] + bf2f(qkws_ro[(size_t)row * 1024 + jn]);
                }
            }
    } else {
        float rsum[2][NCT / 4][4];
        if constexpr (MODE == MQK) {
#pragma unroll
            for (int mt = 0; mt < 2; ++mt)
#pragma unroll
                for (int hg = 0; hg < NCT / 4; ++hg)
#pragma unroll
                    for (int r = 0; r < 4; ++r) rsum[mt][hg][r] = 0.f;
        }
        __syncthreads();   // final-buf reads (buf0) done; C overlays buf1
#pragma unroll
        for (int mt = 0; mt < 2; ++mt)
#pragma unroll
            for (int ct = 0; ct < NCT; ++ct) {
                const int jn = jn0 + ct * 16 + s;
                const float bj = bias[jn];
#pragma unroll
                for (int r = 0; r < 4; ++r) {
                    const int rowl = w * 32 + mt * 16 + quad * 4 + r;
                    float v = acc[mt][ct][r] + bj;
                    if constexpr (MODE == MVU) {
                        const int row = bm + rowl;
                        v *= kg[(((row >> 10) * 8 + (jn >> 6)) << 10) | (row & 1023)];
                    }
                    if constexpr (MODE == MQK) rsum[mt][ct >> 2][r] += v;
                    Cb[rowl * CST + ct * 16 + s] = f2bf(v);
                }
            }
        if constexpr (MODE == MQK) {
            // fused qs/ks: per-row sum over each 64-col head group
#pragma unroll
            for (int mt = 0; mt < 2; ++mt)
#pragma unroll
                for (int hg = 0; hg < NCT / 4; ++hg)
#pragma unroll
                    for (int r = 0; r < 4; ++r) {
                        float S = rsum[mt][hg][r];
                        S += __shfl_xor(S, 1);
                        S += __shfl_xor(S, 2);
                        S += __shfl_xor(S, 4);
                        S += __shfl_xor(S, 8);
                        if (s == 0) {
                            const int row = bm + w * 32 + mt * 16 + quad * 4 + r;
                            const int jj = jn0 + hg * 64;
                            float* dst = (jj < 512) ? qsout : ksout;
                            dst[((((row >> 10) << 3) | ((jj >> 6) & 7)) << 10) | (row & 1023)] = S;
                        }
                    }
        }
        __syncthreads();
        const int row = t >> 1, ch = (t & 1) * (NCT * 8);
        u16* dp = qkws + (size_t)(bm + row) * 1024 + (MODE == MVU ? 512 : 0) + jn0 + ch;
#pragma unroll
        for (int i = 0; i < NCT; ++i)
            *(uint4*)(dp + i * 8) = *(const uint4*)&Cb[row * CST + ch + i * 8];
    }
}

// ---------------------------------------------------------------------------
// stage_gemm: softmax-stage as a chunked GEMM. Block = (128 n-rows, head h);
// grid 512 = 64 n-tiles x 8 heads. Wave owns 32 n-rows x ALL 1024 m.
//   A-tile (q or k slice, 128x64) staged once via gload16+swizzle; A-frags
//   held in registers. B (wq/wk) streamed in 8 chunks of 128 rows through a
//   double-buffered LDS pipeline. Chunk loop is `unroll 1` -- full unroll
//   let the compiler hoist all chunks' bias/wv loads -> 256 VGPR + scratch
//   spill (r12: 219us, 210MB fetch). Per chunk: 32 MFMA + 64 exp + z/w fma
//   per wave; m fully in-wave -> 16-lane shfl reduce; out = W/Z direct.
//   STG=1: l=(q.wq+bq)*S,            wv=qs      -> qg
//   STG=2: l=(rs*(k.wk)+bk)*S, rs=qg, wv=qg*ks  -> kg
// ---------------------------------------------------------------------------
template <int STG>
__global__ __launch_bounds__(256) void stage_gemm(
    const u16* __restrict__ qkws, int qcol0,
    const u16* __restrict__ wmb, const float* __restrict__ biasv,
    const float* __restrict__ rowscale,
    const float* __restrict__ wv1, const float* __restrict__ wv2,
    float* __restrict__ outg)
{
    __shared__ u16 sm[24576];               // A 8192 | Bbuf0 8192 | Bbuf1 8192
    u16* const As = sm;

    const int t = threadIdx.x;
    const int w = t >> 6, lane = t & 63, s = lane & 15, quad = lane >> 4;
    const int sx = lane & 7;
    const int r8 = lane >> 3;
    const int c8x = ((lane & 7) ^ r8) << 3;         // swizzled source chunk (u16)

    // XCD swizzle over 512 blocks
    const int flat = blockIdx.y * gridDim.x + blockIdx.x;
    const int swz = (flat & 7) * 64 + (flat >> 3);
    const int h = swz & 7, bx = swz >> 3;
    const int bm = bx * 128;                        // row in 8192-space
    const int bh = ((bm >> 10) << 3) + h;
    const int n0 = bm & 1023;

    // staging bases: A rows bm+w*32+r8(+8j), 64 cols at qcol0+h*64
    const u16* gA = qkws + (size_t)(bm + w * 32 + r8) * 1024 + qcol0 + (h << 6) + c8x;
    const u16* gB = wmb + (size_t)(w * 32 + r8) * 64 + c8x;

    auto stageB = [&](int buf, int c) {
        u16* lb = sm + 8192 + buf * 8192 + (w * 32) * 64;
        const u16* g = gB + (size_t)c * 128 * 64;
#pragma unroll
        for (int j = 0; j < 4; ++j)
            gload16(g + (size_t)j * 8 * 64, lb + j * 8 * 64);
    };

    // prologue: A once + B chunk0 into buf1
#pragma unroll
    for (int j = 0; j < 4; ++j)
        gload16(gA + (size_t)j * 8 * 1024, As + (w * 32 + j * 8) * 64);
    stageB(1, 0);
    __syncthreads();

    // A fragments in registers for the whole kernel
    short8 a[2][2];
#pragma unroll
    for (int nt = 0; nt < 2; ++nt)
#pragma unroll
        for (int kk = 0; kk < 2; ++kk)
            a[nt][kk] = *(const short8*)&As[(w * 32 + nt * 16 + s) * 64 + (((kk * 4 + quad) ^ sx) << 3)];

    float rsf[2][4];
#pragma unroll
    for (int nt = 0; nt < 2; ++nt)
#pragma unroll
        for (int r = 0; r < 4; ++r) {
            if constexpr (STG == 2)
                rsf[nt][r] = rowscale[(bh << 10) + n0 + w * 32 + nt * 16 + quad * 4 + r] * SCL2;
            else
                rsf[nt][r] = SCL2;
        }

    float z[2][4] = {}, wacc[2][4] = {};

#pragma unroll 1
    for (int c = 0; c < 8; ++c) {
        const int cur = 1 - (c & 1);
        if (c < 7) stageB(1 - cur, c + 1);          // issue next-chunk loads
        __builtin_amdgcn_sched_barrier(0);

        // bias / wv for this chunk (L2-hot, independent loads)
        const int mb = c * 128;
        float bmv[8], wvv[8];
#pragma unroll
        for (int ct = 0; ct < 8; ++ct) {
            const int m = mb + ct * 16 + s;
            bmv[ct] = biasv[m] * SCL2;
            float wv = wv1[(bh << 10) + m];
            if constexpr (STG == 2) wv *= wv2[(bh << 10) + m];
            wvv[ct] = wv;
        }

        const u16* Bb = sm + 8192 + cur * 8192;
#pragma unroll
        for (int ct = 0; ct < 8; ++ct) {
            const short8 b0 = *(const short8*)&Bb[(ct * 16 + s) * 64 + ((quad ^ sx) << 3)];
            const short8 b1 = *(const short8*)&Bb[(ct * 16 + s) * 64 + (((4 + quad) ^ sx) << 3)];
#pragma unroll
            for (int nt = 0; nt < 2; ++nt) {
                f32x4 acc = (f32x4){0.f, 0.f, 0.f, 0.f};
                acc = MFMA16(a[nt][0], b0, acc);
                acc = MFMA16(a[nt][1], b1, acc);
#pragma unroll
                for (int r = 0; r < 4; ++r) {
                    const float e = __builtin_amdgcn_exp2f(rsf[nt][r] * acc[r] + bmv[ct]);
                    z[nt][r] += e;
                    wacc[nt][r] += e * wvv[ct];
                }
            }
        }
        __syncthreads();                            // chunk consumed; WAR-safe
    }

    // reduce over the 16 m-lanes; s==0 writes out = W/Z
#pragma unroll
    for (int nt = 0; nt < 2; ++nt)
#pragma unroll
        for (int r = 0; r < 4; ++r) {
            float Z = z[nt][r], W = wacc[nt][r];
            for (int off = 1; off < 16; off <<= 1) {
                Z += __shfl_xor(Z, off);
                W += __shfl_xor(W, off);
            }
            if (s == 0)
                outg[(bh << 10) + n0 + w * 32 + nt * 16 + quad * 4 + r] = W / Z;
        }
}

// ---------------------------------------------------------------------------
extern "C" void kernel_launch(void* const* d_in, const int* in_sizes, int n_in,
                              void* d_out, int out_size, void* d_ws, size_t ws_size,
                              hipStream_t stream)
{
    const float* x     = (const float*)d_in[0];
    const float* w_qkv = (const float*)d_in[1];
    const float* b_qkv = (const float*)d_in[2];
    const float* wq    = (const float*)d_in[3];
    const float* bq    = (const float*)d_in[4];
    const float* wk    = (const float*)d_in[5];
    const float* bk    = (const float*)d_in[6];
    const float* w_out = (const float*)d_in[7];
    const float* b_out = (const float*)d_in[8];
    float* out = (float*)d_out;

    // ws: qs|ks|qg|kg (65536 f32) | bf16: wqkv|wout|wq|wk|x | qk ws bf16
    float* qs = (float*)d_ws;
    float* ks = qs + 65536;
    float* qg = ks + 65536;
    float* kg = qg + 65536;
    u16* wsb   = (u16*)(kg + 65536);
    u16* wqkvb = wsb;
    u16* woutb = wqkvb + 786432;
    u16* wqb   = woutb + 262144;
    u16* wkb   = wqb + 65536;
    u16* xb    = wkb + 65536;
    u16* qkws  = xb + 4194304;

    // 5,373,952 f32 -> bf16 (weights + x), 4 elems/thread
    conv_kernel<<<5248, 256, 0, stream>>>(w_qkv, w_out, wq, wk, x, wsb);
    // QK: qk = x @ w_qkv[0:1024]^T + b_qkv  (128x128 tile) + fused qs/ks
    gemm_k<MQK, 8><<<dim3(64, 8), 256, 0, stream>>>(
        xb, 512, 0, wqkvb, b_qkv, nullptr, nullptr, qkws, nullptr, qs, ks);
    // stage 1 -> qg
    stage_gemm<1><<<dim3(64, 8), 256, 0, stream>>>(
        qkws, 0, wqb, bq, nullptr, qs, nullptr, qg);
    // stage 2 -> kg
    stage_gemm<2><<<dim3(64, 8), 256, 0, stream>>>(
        qkws, 512, wkb, bk, qg, qg, ks, kg);
    // VU: U = (x @ w_qkv[1024:]^T + bv) * kg  (into k-half of qk ws)
    gemm_k<MVU, 4><<<dim3(64, 8), 256, 0, stream>>>(
        xb, 512, 0, wqkvb + (size_t)1024 * 512, b_qkv + 1024, kg, nullptr, qkws,
        nullptr, nullptr, nullptr);
    // OUT: out = U @ w_out^T + b_out + qo
    gemm_k<MOUT, 4><<<dim3(64, 8), 256, 0, stream>>>(
        qkws, 1024, 512, woutb, b_out, nullptr, qkws, nullptr, out, nullptr, nullptr);
}

// Round 8
// 163.204 us; speedup vs baseline: 3.2554x; 1.0636x over previous
//
#include <hip/hip_runtime.h>

// Fastformer additive attention, MI355X (round 14):
//   - ONE change vs r13: stage_gemm is now 512 threads / 8 waves per
//     128-row block. Waves split the m (ct) dimension: wave w handles
//     rows (w&3)*32..+32 x ct-half (w>>2)*4..+4 of each 128-m chunk.
//     Same per-CU work, 2x waves/SIMD (2 -> 4): MFMA/trans/VALU/LDS pipes
//     can overlap across waves (m114). z/w combine across the two m-halves
//     via a 2KB LDS plane. Chunk loop stays `unroll 1` (r12 spill lesson).
//   - conv / gemm_k (QK, VU, OUT) remain round-9 verbatim.
// Pipeline: conv -> QK(+qsks) -> stage1 -> stage2 -> VU -> OUT  (6 launches)

#define SCL2 0.1803368801f   /* 0.125 * log2(e) */
typedef unsigned short u16;
typedef __attribute__((ext_vector_type(8))) short short8;   // 8 bf16 = 4 VGPR
typedef __attribute__((ext_vector_type(4))) float f32x4;

#define MFMA16(a, b, c) __builtin_amdgcn_mfma_f32_16x16x32_bf16((a), (b), (c), 0, 0, 0)

__device__ __forceinline__ float bf2f(u16 u) {
    union { unsigned int i; float f; } v; v.i = ((unsigned int)u) << 16; return v.f;
}
__device__ __forceinline__ u16 f2bf(float f) {
    union { float f; unsigned int i; } v; v.f = f;
    unsigned int x = v.i;
    return (u16)((x + 0x7FFFu + ((x >> 16) & 1u)) >> 16);
}

// async global->LDS, 16B per lane; LDS dest = wave-uniform base + lane*16
__device__ __forceinline__ void gload16(const u16* g, u16* l) {
    __builtin_amdgcn_global_load_lds(
        (__attribute__((address_space(1))) void*)(void*)g,
        (__attribute__((address_space(3))) void*)l, 16, 0, 0);
}

// ---------------------------------------------------------------------------
// f32 -> bf16: w_qkv | w_out | wq | wk | x   (contiguous ws block)
// ---------------------------------------------------------------------------
__global__ __launch_bounds__(256) void conv_kernel(
    const float* __restrict__ w_qkv, const float* __restrict__ w_out,
    const float* __restrict__ wq, const float* __restrict__ wk,
    const float* __restrict__ x, u16* __restrict__ wsb)
{
    const int idx = (blockIdx.x * 256 + threadIdx.x) * 4;
    const float* src; int off;
    if      (idx < 786432)  { src = w_qkv; off = idx; }
    else if (idx < 1048576) { src = w_out; off = idx - 786432; }
    else if (idx < 1114112) { src = wq;    off = idx - 1048576; }
    else if (idx < 1179648) { src = wk;    off = idx - 1114112; }
    else                    { src = x;     off = idx - 1179648; }
    float4 v = *(const float4*)(src + off);
    ushort4 o; o.x = f2bf(v.x); o.y = f2bf(v.y); o.z = f2bf(v.z); o.w = f2bf(v.w);
    *(ushort4*)(wsb + idx) = o;
}

// ---------------------------------------------------------------------------
// MFMA GEMM (round-9 verbatim): tile 128M x (NCT*16)N, BK=64, K=512, 4 waves.
// Double-buffered gload_lds staging (linear LDS dest, source chunk swizzled
// with (lane&7)^(lane>>3)); fragment reads XOR chunk idx with (row&7).
// K-loop: stage(next buf) -> sched_barrier -> compute(cur) -> syncthreads.
// Final compute reads buf0; C bounce (padded stride) overlays buf1.
// ---------------------------------------------------------------------------
#define MQK 0
#define MVU 1
#define MOUT 2

template <int MODE, int NCT>
__global__ __launch_bounds__(256) void gemm_k(
    const u16* __restrict__ Ab, int lda, int acol,
    const u16* __restrict__ Wb, const float* __restrict__ bias,
    const float* __restrict__ kg, const u16* __restrict__ qkws_ro,
    u16* __restrict__ qkws, float* __restrict__ outp,
    float* __restrict__ qsout, float* __restrict__ ksout)
{
    constexpr int BN = NCT * 16;            // tile N
    constexpr int CST = BN + 8;             // padded bounce stride (u16)
    constexpr int ASZ = 128 * 64;           // A elems per buffer
    constexpr int BSZ = BN * 64;            // B elems per buffer
    constexpr int HALF = ASZ + BSZ;         // one double-buffer half
    constexpr int CELEM = 128 * CST;
    constexpr int SMSZ = (2 * HALF > HALF + CELEM) ? 2 * HALF : HALF + CELEM;
    __shared__ u16 sm[SMSZ];
    u16* const Cb = sm + HALF;              // C bounce overlays buf1 only

    const int t = threadIdx.x;
    const int w = t >> 6, lane = t & 63, s = lane & 15, quad = lane >> 4;
    const int sx = lane & 7;                // row&7 of every fragment row read

    // T1: bijective XCD swizzle (nwg % 8 == 0)
    const int nwgy = gridDim.y;
    const int nwg = gridDim.x * nwgy;
    const int flat = blockIdx.y * gridDim.x + blockIdx.x;
    const int swz = (flat & 7) * (nwg >> 3) + (flat >> 3);
    const int by = swz % nwgy, bx = swz / nwgy;
    const int bm = bx * 128, jn0 = by * BN;

    const int r8 = lane >> 3;                       // staged row within 8-row group
    const int c8x = ((lane & 7) ^ r8) << 3;         // swizzled source chunk (u16)

    f32x4 acc[2][NCT];
#pragma unroll
    for (int i = 0; i < 2; ++i)
#pragma unroll
        for (int j = 0; j < NCT; ++j) acc[i][j] = (f32x4){0.f, 0.f, 0.f, 0.f};

    // per-wave staging bases: A rows [w*32, w*32+32), B rows [w*NCT*4, ...)
    const u16* ga = Ab + (size_t)(bm + w * 32 + r8) * lda + acol + c8x;
    const u16* gb = Wb + (size_t)(jn0 + w * (NCT * 4) + r8) * 512 + c8x;

    auto stage = [&](int buf, int kt) {
        u16* la = sm + buf * HALF + (w * 32) * 64;
        u16* lb = sm + buf * HALF + ASZ + (w * (NCT * 4)) * 64;
#pragma unroll
        for (int j = 0; j < 4; ++j)
            gload16(ga + (size_t)j * 8 * lda + kt, la + j * 8 * 64);
#pragma unroll
        for (int j = 0; j < NCT / 2; ++j)
            gload16(gb + (size_t)j * 8 * 512 + kt, lb + j * 8 * 64);
    };
    auto compute = [&](int buf) {
        const u16* Ab_ = sm + buf * HALF;
        const u16* Bb_ = Ab_ + ASZ;
#pragma unroll
        for (int kk = 0; kk < 2; ++kk) {
            const int ca = ((kk * 4 + quad) ^ sx) << 3;   // swizzled read chunk
            short8 a0 = *(const short8*)&Ab_[(w * 32 + s) * 64 + ca];
            short8 a1 = *(const short8*)&Ab_[(w * 32 + 16 + s) * 64 + ca];
#pragma unroll
            for (int ct = 0; ct < NCT; ++ct) {
                short8 bf = *(const short8*)&Bb_[(ct * 16 + s) * 64 + ca];
                acc[0][ct] = MFMA16(a0, bf, acc[0][ct]);
                acc[1][ct] = MFMA16(a1, bf, acc[1][ct]);
            }
        }
    };

    // Pipeline: prologue stages tile0 into buf1; computes alternate 1,0,1,...
    stage(1, 0);
    __syncthreads();
#pragma unroll
    for (int it = 0; it < 7; ++it) {
        const int cur = 1 - (it & 1);
        stage(1 - cur, 64 * (it + 1));            // issue next-tile loads
        __builtin_amdgcn_sched_barrier(0);        // pin issue-before-compute
        compute(cur);
        __syncthreads();                          // drains prefetch; guards WAR
    }
    compute(0);

    if constexpr (MODE == MOUT) {
#pragma unroll
        for (int mt = 0; mt < 2; ++mt)
#pragma unroll
            for (int ct = 0; ct < NCT; ++ct) {
                const int jn = jn0 + ct * 16 + s;
#pragma unroll
                for (int r = 0; r < 4; ++r) {
                    const int row = bm + w * 32 + mt * 16 + quad * 4 + r;
                    outp[(size_t)row * 512 + jn] =
                        acc[mt][ct][r] + bias[jn] + bf2f(qkws_ro[(size_t)row * 1024 + jn]);
                }
            }
    } else {
        float rsum[2][NCT / 4][4];
        if constexpr (MODE == MQK) {
#pragma unroll
            for (int mt = 0; mt < 2; ++mt)
#pragma unroll
                for (int hg = 0; hg < NCT / 4; ++hg)
#pragma unroll
                    for (int r = 0; r < 4; ++r) rsum[mt][hg][r] = 0.f;
        }
        __syncthreads();   // final-buf reads (buf0) done; C overlays buf1
#pragma unroll
        for (int mt = 0; mt < 2; ++mt)
#pragma unroll
            for (int ct = 0; ct < NCT; ++ct) {
                const int jn = jn0 + ct * 16 + s;
                const float bj = bias[jn];
#pragma unroll
                for (int r = 0; r < 4; ++r) {
                    const int rowl = w * 32 + mt * 16 + quad * 4 + r;
                    float v = acc[mt][ct][r] + bj;
                    if constexpr (MODE == MVU) {
                        const int row = bm + rowl;
                        v *= kg[(((row >> 10) * 8 + (jn >> 6)) << 10) | (row & 1023)];
                    }
                    if constexpr (MODE == MQK) rsum[mt][ct >> 2][r] += v;
                    Cb[rowl * CST + ct * 16 + s] = f2bf(v);
                }
            }
        if constexpr (MODE == MQK) {
            // fused qs/ks: per-row sum over each 64-col head group
#pragma unroll
            for (int mt = 0; mt < 2; ++mt)
#pragma unroll
                for (int hg = 0; hg < NCT / 4; ++hg)
#pragma unroll
                    for (int r = 0; r < 4; ++r) {
                        float S = rsum[mt][hg][r];
                        S += __shfl_xor(S, 1);
                        S += __shfl_xor(S, 2);
                        S += __shfl_xor(S, 4);
                        S += __shfl_xor(S, 8);
                        if (s == 0) {
                            const int row = bm + w * 32 + mt * 16 + quad * 4 + r;
                            const int jj = jn0 + hg * 64;
                            float* dst = (jj < 512) ? qsout : ksout;
                            dst[((((row >> 10) << 3) | ((jj >> 6) & 7)) << 10) | (row & 1023)] = S;
                        }
                    }
        }
        __syncthreads();
        const int row = t >> 1, ch = (t & 1) * (NCT * 8);
        u16* dp = qkws + (size_t)(bm + row) * 1024 + (MODE == MVU ? 512 : 0) + jn0 + ch;
#pragma unroll
        for (int i = 0; i < NCT; ++i)
            *(uint4*)(dp + i * 8) = *(const uint4*)&Cb[row * CST + ch + i * 8];
    }
}

// ---------------------------------------------------------------------------
// stage_gemm (8-wave): softmax-stage as a chunked GEMM. Block = (128 n-rows,
// head h); grid 512 = 64 n-tiles x 8 heads; 512 threads. Wave w owns rows
// (w&3)*32..+32 and ct-half (w>>2)*4..+4 of each 128-m chunk -> 4 waves/SIMD.
//   A-tile (128x64) staged once via gload16+swizzle; A-frags in regs.
//   B (wq/wk) streamed in 8 chunks of 128 rows, double-buffered (unroll 1 --
//   full unroll hoists bias/wv loads -> spill, r12). Per chunk per wave:
//   16 MFMA + 32 exp + z/w fma. m-halves combine via 2KB LDS plane;
//   out = W/Z written by t<128.
//   STG=1: l=(q.wq+bq)*S,            wv=qs      -> qg
//   STG=2: l=(rs*(k.wk)+bk)*S, rs=qg, wv=qg*ks  -> kg
// ---------------------------------------------------------------------------
template <int STG>
__global__ __launch_bounds__(512) void stage_gemm(
    const u16* __restrict__ qkws, int qcol0,
    const u16* __restrict__ wmb, const float* __restrict__ biasv,
    const float* __restrict__ rowscale,
    const float* __restrict__ wv1, const float* __restrict__ wv2,
    float* __restrict__ outg)
{
    __shared__ u16 sm[24576];               // A 8192 | Bbuf0 8192 | Bbuf1 8192
    __shared__ float zp[2][128], wp[2][128];
    u16* const As = sm;

    const int t = threadIdx.x;
    const int w = t >> 6, lane = t & 63, s = lane & 15, quad = lane >> 4;
    const int sx = lane & 7;
    const int r8 = lane >> 3;
    const int c8x = ((lane & 7) ^ r8) << 3;         // swizzled source chunk (u16)
    const int wr = w & 3;                           // row group (32 rows)
    const int mg = w >> 2;                          // m-half group (4 ct)

    // XCD swizzle over 512 blocks
    const int flat = blockIdx.y * gridDim.x + blockIdx.x;
    const int swz = (flat & 7) * 64 + (flat >> 3);
    const int h = swz & 7, bx = swz >> 3;
    const int bm = bx * 128;                        // row in 8192-space
    const int bh = ((bm >> 10) << 3) + h;
    const int n0 = bm & 1023;

    // staging bases: wave w stages rows w*16..w*16+16 (A and B-chunk)
    const u16* gA = qkws + (size_t)(bm + w * 16 + r8) * 1024 + qcol0 + (h << 6) + c8x;
    const u16* gB = wmb + (size_t)(w * 16 + r8) * 64 + c8x;

    auto stageB = [&](int buf, int c) {
        u16* lb = sm + 8192 + buf * 8192 + (w * 16) * 64;
        const u16* g = gB + (size_t)c * 128 * 64;
#pragma unroll
        for (int j = 0; j < 2; ++j)
            gload16(g + (size_t)j * 8 * 64, lb + j * 8 * 64);
    };

    // prologue: A once + B chunk0 into buf1
#pragma unroll
    for (int j = 0; j < 2; ++j)
        gload16(gA + (size_t)j * 8 * 1024, As + (w * 16 + j * 8) * 64);
    stageB(1, 0);
    __syncthreads();

    // A fragments in registers for the whole kernel (rows wr*32..+32)
    short8 a[2][2];
#pragma unroll
    for (int nt = 0; nt < 2; ++nt)
#pragma unroll
        for (int kk = 0; kk < 2; ++kk)
            a[nt][kk] = *(const short8*)&As[(wr * 32 + nt * 16 + s) * 64 + (((kk * 4 + quad) ^ sx) << 3)];

    float rsf[2][4];
#pragma unroll
    for (int nt = 0; nt < 2; ++nt)
#pragma unroll
        for (int r = 0; r < 4; ++r) {
            if constexpr (STG == 2)
                rsf[nt][r] = rowscale[(bh << 10) + n0 + wr * 32 + nt * 16 + quad * 4 + r] * SCL2;
            else
                rsf[nt][r] = SCL2;
        }

    float z[2][4] = {}, wacc[2][4] = {};
    const int ct0 = mg * 4;                         // this wave's ct-half

#pragma unroll 1
    for (int c = 0; c < 8; ++c) {
        const int cur = 1 - (c & 1);
        if (c < 7) stageB(1 - cur, c + 1);          // issue next-chunk loads
        __builtin_amdgcn_sched_barrier(0);

        // bias / wv for this wave's ct-half (L2-hot)
        float bmv[4], wvv[4];
#pragma unroll
        for (int i = 0; i < 4; ++i) {
            const int m = c * 128 + (ct0 + i) * 16 + s;
            bmv[i] = biasv[m] * SCL2;
            float wv = wv1[(bh << 10) + m];
            if constexpr (STG == 2) wv *= wv2[(bh << 10) + m];
            wvv[i] = wv;
        }

        const u16* Bb = sm + 8192 + cur * 8192;
#pragma unroll
        for (int i = 0; i < 4; ++i) {
            const int ct = ct0 + i;
            const short8 b0 = *(const short8*)&Bb[(ct * 16 + s) * 64 + ((quad ^ sx) << 3)];
            const short8 b1 = *(const short8*)&Bb[(ct * 16 + s) * 64 + (((4 + quad) ^ sx) << 3)];
#pragma unroll
            for (int nt = 0; nt < 2; ++nt) {
                f32x4 acc = (f32x4){0.f, 0.f, 0.f, 0.f};
                acc = MFMA16(a[nt][0], b0, acc);
                acc = MFMA16(a[nt][1], b1, acc);
#pragma unroll
                for (int r = 0; r < 4; ++r) {
                    const float e = __builtin_amdgcn_exp2f(rsf[nt][r] * acc[r] + bmv[i]);
                    z[nt][r] += e;
                    wacc[nt][r] += e * wvv[i];
                }
            }
        }
        __syncthreads();                            // chunk consumed; WAR-safe
    }

    // reduce over the 16 m-lanes; s==0 writes the wave's partial plane
#pragma unroll
    for (int nt = 0; nt < 2; ++nt)
#pragma unroll
        for (int r = 0; r < 4; ++r) {
            float Z = z[nt][r], W = wacc[nt][r];
            for (int off = 1; off < 16; off <<= 1) {
                Z += __shfl_xor(Z, off);
                W += __shfl_xor(W, off);
            }
            if (s == 0) {
                const int rowl = wr * 32 + nt * 16 + quad * 4 + r;
                zp[mg][rowl] = Z;
                wp[mg][rowl] = W;
            }
        }
    __syncthreads();
    if (t < 128) {
        const float Z = zp[0][t] + zp[1][t];
        const float W = wp[0][t] + wp[1][t];
        outg[(bh << 10) + n0 + t] = W / Z;
    }
}

// ---------------------------------------------------------------------------
extern "C" void kernel_launch(void* const* d_in, const int* in_sizes, int n_in,
                              void* d_out, int out_size, void* d_ws, size_t ws_size,
                              hipStream_t stream)
{
    const float* x     = (const float*)d_in[0];
    const float* w_qkv = (const float*)d_in[1];
    const float* b_qkv = (const float*)d_in[2];
    const float* wq    = (const float*)d_in[3];
    const float* bq    = (const float*)d_in[4];
    const float* wk    = (const float*)d_in[5];
    const float* bk    = (const float*)d_in[6];
    const float* w_out = (const float*)d_in[7];
    const float* b_out = (const float*)d_in[8];
    float* out = (float*)d_out;

    // ws: qs|ks|qg|kg (65536 f32) | bf16: wqkv|wout|wq|wk|x | qk ws bf16
    float* qs = (float*)d_ws;
    float* ks = qs + 65536;
    float* qg = ks + 65536;
    float* kg = qg + 65536;
    u16* wsb   = (u16*)(kg + 65536);
    u16* wqkvb = wsb;
    u16* woutb = wqkvb + 786432;
    u16* wqb   = woutb + 262144;
    u16* wkb   = wqb + 65536;
    u16* xb    = wkb + 65536;
    u16* qkws  = xb + 4194304;

    // 5,373,952 f32 -> bf16 (weights + x), 4 elems/thread
    conv_kernel<<<5248, 256, 0, stream>>>(w_qkv, w_out, wq, wk, x, wsb);
    // QK: qk = x @ w_qkv[0:1024]^T + b_qkv  (128x128 tile) + fused qs/ks
    gemm_k<MQK, 8><<<dim3(64, 8), 256, 0, stream>>>(
        xb, 512, 0, wqkvb, b_qkv, nullptr, nullptr, qkws, nullptr, qs, ks);
    // stage 1 -> qg
    stage_gemm<1><<<dim3(64, 8), 512, 0, stream>>>(
        qkws, 0, wqb, bq, nullptr, qs, nullptr, qg);
    // stage 2 -> kg
    stage_gemm<2><<<dim3(64, 8), 512, 0, stream>>>(
        qkws, 512, wkb, bk, qg, qg, ks, kg);
    // VU: U = (x @ w_qkv[1024:]^T + bv) * kg  (into k-half of qk ws)
    gemm_k<MVU, 4><<<dim3(64, 8), 256, 0, stream>>>(
        xb, 512, 0, wqkvb + (size_t)1024 * 512, b_qkv + 1024, kg, nullptr, qkws,
        nullptr, nullptr, nullptr);
    // OUT: out = U @ w_out^T + b_out + qo
    gemm_k<MOUT, 4><<<dim3(64, 8), 256, 0, stream>>>(
        qkws, 1024, 512, woutb, b_out, nullptr, qkws, nullptr, out, nullptr, nullptr);
}